// Round 10
// baseline (731.709 us; speedup 1.0000x reference)
//
#include <hip/hip_runtime.h>
#include <stdint.h>

#define T_SEQ 4096
#define HID   2048
#define NH    16
#define HD    128

typedef __attribute__((ext_vector_type(8))) short short8;
typedef __attribute__((ext_vector_type(4))) short short4v;
typedef __attribute__((ext_vector_type(4))) float f32x4;
typedef __attribute__((ext_vector_type(4))) unsigned int uint4v;

typedef __attribute__((address_space(1))) void as1_void;
typedef __attribute__((address_space(3))) void as3_void;

__device__ __forceinline__ unsigned short f2bf(float f){
  unsigned u = __builtin_bit_cast(unsigned, f);
  u += 0x7fffu + ((u >> 16) & 1u);
  return (unsigned short)(u >> 16);
}
__device__ __forceinline__ float bf2f(unsigned short b){
  unsigned u = ((unsigned)b) << 16;
  return __builtin_bit_cast(float, u);
}
// pack two floats to 2 bf16 in one u32 (truncation — matches prior P path)
__device__ __forceinline__ unsigned pk2(float a, float b){
  return (__builtin_bit_cast(unsigned, a) >> 16) |
         (__builtin_bit_cast(unsigned, b) & 0xffff0000u);
}
// async global->LDS, 16B per lane. LDS side is wave-uniform base + lane*16.
__device__ __forceinline__ void gll16(const void* g, void* l){
  __builtin_amdgcn_global_load_lds((as1_void*)(uintptr_t)g,
                                   (as3_void*)(unsigned)(uintptr_t)l, 16, 0, 0);
}

#define VM_WAIT0    asm volatile("s_waitcnt vmcnt(0)" ::: "memory")
#define LGKM_WAIT0  asm volatile("s_waitcnt lgkmcnt(0)" ::: "memory")
__device__ __forceinline__ void barrier_fence(){
  asm volatile("" ::: "memory");
  __builtin_amdgcn_s_barrier();
  asm volatile("" ::: "memory");
}

// ---------------- fp32 -> bf16 conversion of X ----------------
__global__ __launch_bounds__(256) void conv_x_k(const float* __restrict__ X,
                                                unsigned short* __restrict__ O){
  int i = (blockIdx.x * 256 + threadIdx.x) * 4;
  float4 v = *(const float4*)(X + i);
  short4v o;
  o[0] = (short)f2bf(v.x); o[1] = (short)f2bf(v.y);
  o[2] = (short)f2bf(v.z); o[3] = (short)f2bf(v.w);
  *(short4v*)(O + i) = o;
}

// ------------- weight transpose + bf16: W[k][n] -> Wt[n][k] -------------
__global__ __launch_bounds__(256) void conv_wt_k(const float* __restrict__ W0,
                                                 const float* __restrict__ W1,
                                                 const float* __restrict__ W2,
                                                 const float* __restrict__ W3,
                                                 unsigned short* __restrict__ Wt){
  const float* W = (blockIdx.z == 0) ? W0 : (blockIdx.z == 1) ? W1
                   : (blockIdx.z == 2) ? W2 : W3;
  unsigned short* out = Wt + (size_t)blockIdx.z * HID * HID;
  __shared__ float tile[32][33];
  const int x = threadIdx.x;       // 0..31
  const int y = threadIdx.y;       // 0..7
  const int k0 = blockIdx.y * 32, n0 = blockIdx.x * 32;
#pragma unroll
  for (int i = 0; i < 4; ++i){
    int r = y * 4 + i;
    tile[r][x] = W[(size_t)(k0 + r) * HID + n0 + x];
  }
  __syncthreads();
#pragma unroll
  for (int i = 0; i < 4; ++i){
    int r = y * 4 + i;
    out[(size_t)(n0 + r) * HID + k0 + x] = f2bf(tile[x][r]);
  }
}

// ---------------- GEMM: C[M][N] = A[M][K=2048] * Bt[N][K]^T ----------------
// 128x128 tile, 4 waves (2x2), BK=64 (32 iters), global_load_lds(16B).
// LDS slot (row, c) holds global chunk c ^ (row&7); fragment read chunk
// (ks*4+qd) ^ (mm&7) -> bank-uniform.
// R9 finding: XCD-chunked swizzle REGRESSED (-16us). With gridDim.x % 8 == 0,
// linear dispatch already gives each XCD a fixed residue class of bn columns
// (6 cols x 0.5MB B-panels L2-resident, reused across all by-rows); the chunk
// remap destroyed B-residency for a worse A-residency trade. Linear mapping.
// MODE 0: Q/K blocks scatter bf16 [h][t][d]; V blocks (bn>=4096) transpose
//   the 128x128 tile through LDS (chunk-XOR swizzle) and store Vt [h][d][t]
//   as 256B-contiguous runs.
// MODE 1: epilogue writes fp32 C row-major [M][NTOT].
template<int MODE, int NTOT>
__global__ __launch_bounds__(256, 3) void gemm_bt(
    const unsigned short* __restrict__ A,
    const unsigned short* __restrict__ Bt,
    unsigned short* __restrict__ Qb,
    unsigned short* __restrict__ Kb,
    unsigned short* __restrict__ Vt,
    float* __restrict__ Cf)
{
  constexpr int K = HID;
  __shared__ __align__(16) unsigned short lAB[16384];   // lA | lB ; reused as lT
  unsigned short* lA = lAB;
  unsigned short* lB = lAB + 8192;

  const int tid  = threadIdx.x;
  const int wave = tid >> 6;
  const int lane = tid & 63;
  const int qd   = lane >> 4;
  const int mm   = lane & 15;
  const int m7   = mm & 7;
  const int wm   = wave >> 1;
  const int wn   = wave & 1;
  const int bm   = blockIdx.y * 128;
  const int bn   = blockIdx.x * 128;

  const unsigned short* ga[4];
  const unsigned short* gb[4];
  unsigned short* la[4];
  unsigned short* lbp[4];
#pragma unroll
  for (int i = 0; i < 4; ++i){
    int s0   = (wave * 4 + i) * 64;   // wave-uniform base slot
    int slot = s0 + lane;
    int row  = slot >> 3;
    int kb   = (slot & 7) ^ (row & 7);
    ga[i]  = A  + (size_t)(bm + row) * K + kb * 8;
    gb[i]  = Bt + (size_t)(bn + row) * K + kb * 8;
    la[i]  = lA + s0 * 8;
    lbp[i] = lB + s0 * 8;
  }

  int abase[4], bbase[4];
#pragma unroll
  for (int t = 0; t < 4; ++t){
    abase[t] = (wm * 64 + t * 16 + mm) * 8;
    bbase[t] = (wn * 64 + t * 16 + mm) * 8;
  }

  const f32x4 fzero = {0.f, 0.f, 0.f, 0.f};
  f32x4 acc[4][4];
#pragma unroll
  for (int i = 0; i < 4; ++i)
#pragma unroll
    for (int j = 0; j < 4; ++j) acc[i][j] = fzero;

  for (int k0 = 0; k0 < K; k0 += 64){
    __syncthreads();
#pragma unroll
    for (int i = 0; i < 4; ++i){
      gll16(ga[i] + k0, la[i]);
      gll16(gb[i] + k0, lbp[i]);
    }
    __syncthreads();
#pragma unroll
    for (int ks = 0; ks < 2; ++ks){
      const int co = (ks * 4 + qd) ^ m7;
      short8 af[4], bfv[4];
#pragma unroll
      for (int t = 0; t < 4; ++t) af[t]  = *(const short8*)(lA + (abase[t] + co) * 8);
#pragma unroll
      for (int t = 0; t < 4; ++t) bfv[t] = *(const short8*)(lB + (bbase[t] + co) * 8);
#pragma unroll
      for (int i = 0; i < 4; ++i)
#pragma unroll
        for (int j = 0; j < 4; ++j)
          acc[i][j] = __builtin_amdgcn_mfma_f32_16x16x32_bf16(af[i], bfv[j], acc[i][j], 0, 0, 0);
    }
  }

  if (MODE == 0 && bn >= 4096){
    // ---- V block: 128x128 tile transpose via LDS, coalesced Vt stores ----
    __syncthreads();   // all lA/lB fragment reads done before overwrite
    unsigned short* lT = lAB;   // [d=128][t-chunks 32][4] u16, chunk XOR swz
#pragma unroll
    for (int i = 0; i < 4; ++i){
#pragma unroll
      for (int j = 0; j < 4; ++j){
        const int d_l   = wn * 64 + j * 16 + mm;
        const int chunk = wm * 16 + i * 4 + qd;     // t_local>>2
        const int ch    = chunk ^ (d_l & 31);
        short4v pk;
#pragma unroll
        for (int r = 0; r < 4; ++r) pk[r] = (short)f2bf(acc[i][j][r]);
        *(short4v*)(lT + d_l * 128 + ch * 4) = pk;
      }
    }
    __syncthreads();
    const int hV = (bn >> 7) - 32;
    const int dd = tid >> 4;          // 0..15
    const int tg = tid & 15;          // 8-t group -> 16B store
#pragma unroll
    for (int p = 0; p < 8; ++p){
      const int d_l = p * 16 + dd;
      const int c0  = (tg * 2)     ^ (d_l & 31);
      const int c1  = (tg * 2 + 1) ^ (d_l & 31);
      short4v lo = *(const short4v*)(lT + d_l * 128 + c0 * 4);
      short4v hi = *(const short4v*)(lT + d_l * 128 + c1 * 4);
      short8 ov;
      ov[0] = lo[0]; ov[1] = lo[1]; ov[2] = lo[2]; ov[3] = lo[3];
      ov[4] = hi[0]; ov[5] = hi[1]; ov[6] = hi[2]; ov[7] = hi[3];
      *(short8*)(Vt + ((size_t)(hV * HD + d_l)) * T_SEQ + bm + tg * 8) = ov;
    }
    return;
  }

#pragma unroll
  for (int i = 0; i < 4; ++i){
#pragma unroll
    for (int j = 0; j < 4; ++j){
      const int col = bn + wn * 64 + j * 16 + mm;
#pragma unroll
      for (int r = 0; r < 4; ++r){
        const int row = bm + wm * 64 + i * 16 + qd * 4 + r;
        const float v = acc[i][j][r];
        if (MODE == 0){
          const int nn  = col & 2047;
          const int h   = nn >> 7;
          const int d   = nn & 127;
          const unsigned short bv = f2bf(v);
          if (col < 2048)      Qb[((size_t)h * T_SEQ + row) * HD + d] = bv;
          else                 Kb[((size_t)h * T_SEQ + row) * HD + d] = bv;
        } else {
          Cf[(size_t)row * NTOT + col] = v;
        }
      }
    }
  }
}

// ---------------- RoPE on Q and K (in place, bf16) ----------------
__global__ __launch_bounds__(256) void rope_k(unsigned short* __restrict__ Qb,
                                              unsigned short* __restrict__ Kb){
  const int j = threadIdx.x & 63;
  const int t = blockIdx.x * 4 + (threadIdx.x >> 6);
  const int h = blockIdx.y;
  const float fr = (float)t * __expf(-(float)j * (9.210340371976184f / 64.f));
  const float cs = cosf(fr), sn = sinf(fr);
  const size_t base = ((size_t)h * T_SEQ + t) * HD;
  {
    float x1 = bf2f(Qb[base + j]), x2 = bf2f(Qb[base + j + 64]);
    Qb[base + j]      = f2bf(x1 * cs - x2 * sn);
    Qb[base + j + 64] = f2bf(x2 * cs + x1 * sn);
  }
  {
    float x1 = bf2f(Kb[base + j]), x2 = bf2f(Kb[base + j + 64]);
    Kb[base + j]      = f2bf(x1 * cs - x2 * sn);
    Kb[base + j + 64] = f2bf(x2 * cs + x1 * sn);
  }
}

// ---------------- flash attention v10 (in-register P, no lP) ----------------
// Invariant 132us across v6/v7/v8 schedules -> per-CU throughput bound; LDS
// issue + the softmax->lP-write->lgkm-wait->lP-read->PV serialization is the
// remaining suspect. v10 removes the lP round-trip entirely:
//  - SWAPPED QK^T: St[nt][mt] = mfma(kf, qf) (K as A-operand, Q as B). Lane
//    (qd,cc) then holds P for q-row cc at keys nt*16+qd*4+r = exactly its 8
//    PV A-fragment slots.
//  - k-SLOT PERMUTATION (both-sides-consistent): pf packs the lane's native
//    8 values in-register (4 pk2, zero shuffles); vf is read as two
//    ds_read_b64 halves so slot (qd,e) carries the SAME permuted key
//    kg*32 + (e>=4)*16 + qd*4 + (e&3). MFMA contracts over slots ->
//    permutation-invariant; ones-MFMA row-sum (acc_l) likewise. Numerics
//    identical (same bf16 truncation as the old stored-P path).
//  - lP freed: smem 41216 -> 35072 B -> 4 blocks/CU (grid 1024 = exactly 4).
// Block = 4 waves = 2 row-groups (rg) x 2 key-groups (kg); grid 1024 =
// 16 heads x 64 q-tiles, big tiles first; h&7 = b&7 XCD pinning.
__global__ __launch_bounds__(256, 4) void attn_k(
    const unsigned short* __restrict__ Qb,   // [NH][T][HD]
    const unsigned short* __restrict__ Kb,   // [NH][T][HD]
    const unsigned short* __restrict__ Vt,   // [NH][HD][T]
    unsigned short* __restrict__ Yb)         // [T][HID]
{
  __shared__ __align__(16) unsigned char smem[35072];
  unsigned short* lK = (unsigned short*)smem;              // [64 keys][128 d] 16 KB
  unsigned short* lV = (unsigned short*)(smem + 16384);    // [128 d][64 keys] 16 KB
  float* lO = (float*)smem;                                // [128 d][68] epilogue overlay
  float* lL = (float*)(smem + 34816);                      // [64] (beyond lO)

  const int tid  = threadIdx.x;
  const int w    = tid >> 6;
  const int rg   = w >> 1;
  const int kg   = w & 1;
  const int lane = tid & 63;
  const int qd   = lane >> 4;
  const int cc   = lane & 15;
  const int cx   = cc & 7;
  const int r8   = lane >> 3, c7 = lane & 7;

  const int b  = blockIdx.x;            // 1024 blocks
  const int h  = b & 15;                // head; h&7 = b&7 -> XCD pinned
  const int tp = 63 - (b >> 4);         // big tiles dispatched first
  const int qrow0 = tp * 64 + rg * 32;
  const int iters = tp + 1;

  // staging source addressing (swizzle on fetch side; slot chunk c holds
  // global chunk c ^ (row&7))
  const int ce  = cc ^ qd;
  const int dlt = (ce & 4) ? -32 : 32;
  const unsigned short* gKbp = Kb + ((size_t)h * T_SEQ + w * 16 + qd) * HD + ce * 8;
  const int cV = c7 ^ r8;
  const unsigned short* gVbp = Vt + ((size_t)h * HD + w * 32 + r8) * T_SEQ + cV * 8;

  // vf half-chunk addressing (permuted-k layout): slot e<4 -> key qd*4+e,
  // slot e>=4 -> key 16+qd*4+(e&3), within kg's 32 keys.
  const int cgA = kg * 4 + (qd >> 1);       // global 8-key chunk of lower half
  const int vhalf = (qd & 1) * 4;           // 4-short offset within chunk

  const f32x4 fzero = {0.f, 0.f, 0.f, 0.f};
  // 50*tanh(s*SCALE/50)*log2(e) ~= s*(B0 + B1*s^2 + B2*s^4)
  const float B0 = 0.09016844006f;
  const float B1 = -4.6962728e-8f;
  const float B2 = 2.9351706e-14f;
  const float CLP = 72.134752f;        // 50 * log2(e)
  short8 onesv;
#pragma unroll
  for (int j = 0; j < 8; ++j) onesv[j] = (short)0x3F80;    // bf16 1.0

  // prologue: stage K(0), V(0)
  {
    unsigned short* dK = lK + w * 2048;
#pragma unroll
    for (int i = 0; i < 4; ++i)
      gll16(gKbp + (size_t)(i * 4) * HD + ((i & 1) ? dlt : 0), dK + i * 512);
    unsigned short* dV = lV + w * 2048;
#pragma unroll
    for (int i = 0; i < 4; ++i)
      gll16(gVbp + (size_t)i * 8 * T_SEQ, dV + i * 512);
  }

  // Q fragments: rows qrow0 + mt*16 + cc, d = ks*32 + qd*8 (B-operand now)
  short8 qf[2][4];
#pragma unroll
  for (int mt = 0; mt < 2; ++mt)
#pragma unroll
    for (int ks = 0; ks < 4; ++ks)
      qf[mt][ks] = *(const short8*)(Qb + ((size_t)h * T_SEQ + qrow0 + mt * 16 + cc) * HD + ks * 32 + qd * 8);

  f32x4 o[2][8];
  f32x4 acc_l[2];
#pragma unroll
  for (int mt = 0; mt < 2; ++mt){
#pragma unroll
    for (int dn = 0; dn < 8; ++dn) o[mt][dn] = fzero;
    acc_l[mt] = fzero;
  }

#pragma unroll 1
  for (int it = 0; it < iters; ++it){
    const int k0 = it * 64;
    VM_WAIT0;          // this wave's K(it)/V(it) landed
    barrier_fence();   // all waves' landed; tiles valid

    // St = (Q K^T)^T via swapped operands: St[nt][mt], lane holds
    // key = k0 + kg*32 + nt*16 + qd*4 + r, q-row = qrow0 + mt*16 + cc
    f32x4 St[2][2];
#pragma unroll
    for (int nt = 0; nt < 2; ++nt)
#pragma unroll
      for (int mt = 0; mt < 2; ++mt) St[nt][mt] = fzero;
    __builtin_amdgcn_s_setprio(1);
#pragma unroll
    for (int nt = 0; nt < 2; ++nt){
      short8 kf[4];
#pragma unroll
      for (int ks = 0; ks < 4; ++ks)
        kf[ks] = *(const short8*)(lK + ((kg * 32 + nt * 16 + cc) * 16 + ((ks * 4 + qd) ^ cx)) * 8);
#pragma unroll
      for (int mt = 0; mt < 2; ++mt)
#pragma unroll
        for (int ks = 0; ks < 4; ++ks)
          St[nt][mt] = __builtin_amdgcn_mfma_f32_16x16x32_bf16(kf[ks], qf[mt][ks], St[nt][mt], 0, 0, 0);
    }
    __builtin_amdgcn_s_setprio(0);

    // softcap + exp2 + causal mask (last iter), then in-register bf16 pack
    const bool domask = (it == iters - 1);
    short8 pf[2];
#pragma unroll
    for (int mt = 0; mt < 2; ++mt){
      float pv[2][4];
#pragma unroll
      for (int nt = 0; nt < 2; ++nt)
#pragma unroll
        for (int r = 0; r < 4; ++r){
          float s = St[nt][mt][r];
          float w2 = s * s;
          float t = fmaf(w2, B2, B1);
          t = fmaf(w2, t, B0);
          float a = s * t;
          a = __builtin_amdgcn_fmed3f(a, -CLP, CLP);
          float p = __builtin_amdgcn_exp2f(a);
          if (domask){
            int key = k0 + kg * 32 + nt * 16 + qd * 4 + r;
            int row = qrow0 + mt * 16 + cc;
            if (key > row) p = 0.f;
          }
          pv[nt][r] = p;
        }
      uint4v up;
      up[0] = pk2(pv[0][0], pv[0][1]);
      up[1] = pk2(pv[0][2], pv[0][3]);
      up[2] = pk2(pv[1][0], pv[1][1]);
      up[3] = pk2(pv[1][2], pv[1][3]);
      pf[mt] = __builtin_bit_cast(short8, up);
    }

    // O += P V (permuted-k vf: two b64 halves per dn) ; l += P . 1
    __builtin_amdgcn_s_setprio(1);
#pragma unroll
    for (int dn = 0; dn < 8; ++dn){
      const int drow = (dn * 16 + cc) * 8;
      short4v vlo = *(const short4v*)(lV + (drow + (cgA ^ cx)) * 8 + vhalf);
      short4v vhi = *(const short4v*)(lV + (drow + ((cgA + 2) ^ cx)) * 8 + vhalf);
      short8 vfv;
      vfv[0] = vlo[0]; vfv[1] = vlo[1]; vfv[2] = vlo[2]; vfv[3] = vlo[3];
      vfv[4] = vhi[0]; vfv[5] = vhi[1]; vfv[6] = vhi[2]; vfv[7] = vhi[3];
#pragma unroll
      for (int mt = 0; mt < 2; ++mt)
        o[mt][dn] = __builtin_amdgcn_mfma_f32_16x16x32_bf16(pf[mt], vfv, o[mt][dn], 0, 0, 0);
    }
#pragma unroll
    for (int mt = 0; mt < 2; ++mt)
      acc_l[mt] = __builtin_amdgcn_mfma_f32_16x16x32_bf16(pf[mt], onesv, acc_l[mt], 0, 0, 0);
    __builtin_amdgcn_s_setprio(0);

    // all lK/lV ds_reads retired, then barrier: next iter's global_load_lds
    // writes must not land before every wave's reads are done
    LGKM_WAIT0;
    barrier_fence();

    if (it + 1 < iters){
      const unsigned short* gK = gKbp + (size_t)(k0 + 64) * HD;
      unsigned short* dK = lK + w * 2048;
#pragma unroll
      for (int i = 0; i < 4; ++i)
        gll16(gK + (size_t)(i * 4) * HD + ((i & 1) ? dlt : 0), dK + i * 512);
      const unsigned short* gV = gVbp + (k0 + 64);
      unsigned short* dV = lV + w * 2048;
#pragma unroll
      for (int i = 0; i < 4; ++i)
        gll16(gV + (size_t)i * 8 * T_SEQ, dV + i * 512);
    }
  }

  // ---- epilogue: merge kg partials (additive), normalize, store ----
  // acc_l[mt][r] = row-sum for q-row mt*16+qd*4+r (same value in all cc)
  __syncthreads();   // all K/V traffic done before lO overlays the region
  if (kg == 1){
#pragma unroll
    for (int mt = 0; mt < 2; ++mt){
#pragma unroll
      for (int dn = 0; dn < 8; ++dn)
        *(f32x4*)&lO[(dn * 16 + cc) * 68 + rg * 32 + mt * 16 + qd * 4] = o[mt][dn];
      if (cc == 0){
#pragma unroll
        for (int r = 0; r < 4; ++r)
          lL[rg * 32 + mt * 16 + qd * 4 + r] = acc_l[mt][r];
      }
    }
  }
  __syncthreads();
  if (kg == 0){
#pragma unroll
    for (int mt = 0; mt < 2; ++mt){
      float inv[4];
#pragma unroll
      for (int r = 0; r < 4; ++r){
        float lt = acc_l[mt][r] + lL[rg * 32 + mt * 16 + qd * 4 + r];
        inv[r] = __builtin_amdgcn_rcpf(lt);
      }
#pragma unroll
      for (int dn = 0; dn < 8; ++dn){
        f32x4 oo = o[mt][dn] + *(const f32x4*)&lO[(dn * 16 + cc) * 68 + rg * 32 + mt * 16 + qd * 4];
#pragma unroll
        for (int r = 0; r < 4; ++r){
          int row = qrow0 + mt * 16 + qd * 4 + r;
          Yb[(size_t)row * HID + h * HD + dn * 16 + cc] = f2bf(oo[r] * inv[r]);
        }
      }
    }
  }
}

extern "C" void kernel_launch(void* const* d_in, const int* in_sizes, int n_in,
                              void* d_out, int out_size, void* d_ws, size_t ws_size,
                              hipStream_t stream) {
  const float* X  = (const float*)d_in[0];
  const float* Wq = (const float*)d_in[1];
  const float* Wk = (const float*)d_in[2];
  const float* Wv = (const float*)d_in[3];
  const float* Wo = (const float*)d_in[4];
  float* out = (float*)d_out;

  unsigned short* ws = (unsigned short*)d_ws;
  unsigned short* Xb = ws;                                   // [T][HID]        16 MiB
  unsigned short* Wt = ws + (size_t)8  * 1024 * 1024;        // [4*2048][2048]  32 MiB
  unsigned short* Qb = ws + (size_t)24 * 1024 * 1024;        // [NH][T][HD]     16 MiB
  unsigned short* Kb = ws + (size_t)32 * 1024 * 1024;        // [NH][T][HD]     16 MiB
  unsigned short* Vt = ws + (size_t)40 * 1024 * 1024;        // [NH][HD][T]     16 MiB
  unsigned short* Yb = Xb;                                   // reuse X region

  conv_x_k<<<8192, 256, 0, stream>>>(X, Xb);
  conv_wt_k<<<dim3(64, 64, 4), dim3(32, 8), 0, stream>>>(Wq, Wk, Wv, Wo, Wt);
  gemm_bt<0, 6144><<<dim3(48, 32), 256, 0, stream>>>(Xb, Wt, Qb, Kb, Vt, nullptr);
  rope_k<<<dim3(1024, NH), 256, 0, stream>>>(Qb, Kb);
  attn_k<<<dim3(1024), 256, 0, stream>>>(Qb, Kb, Vt, Yb);
  gemm_bt<1, 2048><<<dim3(16, 32), 256, 0, stream>>>(Yb, Wt + (size_t)6144 * 2048,
                                                     nullptr, nullptr, nullptr, out);
}

// Round 14
// 421.309 us; speedup vs baseline: 1.7367x; 1.7367x over previous
//
#include <hip/hip_runtime.h>
#include <stdint.h>

#define T_SEQ 4096
#define HID   2048
#define NH    16
#define HD    128

typedef __attribute__((ext_vector_type(8))) short short8;
typedef __attribute__((ext_vector_type(4))) short short4v;
typedef __attribute__((ext_vector_type(4))) float f32x4;
typedef __attribute__((ext_vector_type(4))) unsigned int uint4v;

typedef __attribute__((address_space(1))) void as1_void;
typedef __attribute__((address_space(3))) void as3_void;

__device__ __forceinline__ unsigned short f2bf(float f){
  unsigned u = __builtin_bit_cast(unsigned, f);
  u += 0x7fffu + ((u >> 16) & 1u);
  return (unsigned short)(u >> 16);
}
__device__ __forceinline__ float bf2f(unsigned short b){
  unsigned u = ((unsigned)b) << 16;
  return __builtin_bit_cast(float, u);
}
// pack two floats to 2 bf16 in one u32 (truncation — matches prior P path)
__device__ __forceinline__ unsigned pk2(float a, float b){
  return (__builtin_bit_cast(unsigned, a) >> 16) |
         (__builtin_bit_cast(unsigned, b) & 0xffff0000u);
}
// async global->LDS, 16B per lane. LDS side is wave-uniform base + lane*16.
__device__ __forceinline__ void gll16(const void* g, void* l){
  __builtin_amdgcn_global_load_lds((as1_void*)(uintptr_t)g,
                                   (as3_void*)(unsigned)(uintptr_t)l, 16, 0, 0);
}

#define VM_WAIT0    asm volatile("s_waitcnt vmcnt(0)" ::: "memory")
#define LGKM_WAIT0  asm volatile("s_waitcnt lgkmcnt(0)" ::: "memory")
__device__ __forceinline__ void barrier_fence(){
  asm volatile("" ::: "memory");
  __builtin_amdgcn_s_barrier();
  asm volatile("" ::: "memory");
}

// ---------------- fp32 -> bf16 conversion of X ----------------
__global__ __launch_bounds__(256) void conv_x_k(const float* __restrict__ X,
                                                unsigned short* __restrict__ O){
  int i = (blockIdx.x * 256 + threadIdx.x) * 4;
  float4 v = *(const float4*)(X + i);
  short4v o;
  o[0] = (short)f2bf(v.x); o[1] = (short)f2bf(v.y);
  o[2] = (short)f2bf(v.z); o[3] = (short)f2bf(v.w);
  *(short4v*)(O + i) = o;
}

// ------------- weight transpose + bf16: W[k][n] -> Wt[n][k] -------------
__global__ __launch_bounds__(256) void conv_wt_k(const float* __restrict__ W0,
                                                 const float* __restrict__ W1,
                                                 const float* __restrict__ W2,
                                                 const float* __restrict__ W3,
                                                 unsigned short* __restrict__ Wt){
  const float* W = (blockIdx.z == 0) ? W0 : (blockIdx.z == 1) ? W1
                   : (blockIdx.z == 2) ? W2 : W3;
  unsigned short* out = Wt + (size_t)blockIdx.z * HID * HID;
  __shared__ float tile[32][33];
  const int x = threadIdx.x;       // 0..31
  const int y = threadIdx.y;       // 0..7
  const int k0 = blockIdx.y * 32, n0 = blockIdx.x * 32;
#pragma unroll
  for (int i = 0; i < 4; ++i){
    int r = y * 4 + i;
    tile[r][x] = W[(size_t)(k0 + r) * HID + n0 + x];
  }
  __syncthreads();
#pragma unroll
  for (int i = 0; i < 4; ++i){
    int r = y * 4 + i;
    out[(size_t)(n0 + r) * HID + k0 + x] = f2bf(tile[x][r]);
  }
}

// ---------------- GEMM: C[M][N] = A[M][K=2048] * Bt[N][K]^T ----------------
// 128x128 tile, 4 waves (2x2), BK=64 (32 iters), global_load_lds(16B).
// LDS slot (row, c) holds global chunk c ^ (row&7); fragment read chunk
// (ks*4+qd) ^ (mm&7) -> bank-uniform.
// R9 finding: XCD-chunked swizzle REGRESSED (-16us). With gridDim.x % 8 == 0,
// linear dispatch already gives each XCD a fixed residue class of bn columns
// (6 cols x 0.5MB B-panels L2-resident, reused across all by-rows). Linear.
// MODE 0: Q/K blocks scatter bf16 [h][t][d]; V blocks (bn>=4096) transpose
//   the 128x128 tile through LDS (chunk-XOR swizzle) and store Vt [h][d][t]
//   as 256B-contiguous runs.
// MODE 1: epilogue writes fp32 C row-major [M][NTOT].
template<int MODE, int NTOT>
__global__ __launch_bounds__(256, 3) void gemm_bt(
    const unsigned short* __restrict__ A,
    const unsigned short* __restrict__ Bt,
    unsigned short* __restrict__ Qb,
    unsigned short* __restrict__ Kb,
    unsigned short* __restrict__ Vt,
    float* __restrict__ Cf)
{
  constexpr int K = HID;
  __shared__ __align__(16) unsigned short lAB[16384];   // lA | lB ; reused as lT
  unsigned short* lA = lAB;
  unsigned short* lB = lAB + 8192;

  const int tid  = threadIdx.x;
  const int wave = tid >> 6;
  const int lane = tid & 63;
  const int qd   = lane >> 4;
  const int mm   = lane & 15;
  const int m7   = mm & 7;
  const int wm   = wave >> 1;
  const int wn   = wave & 1;
  const int bm   = blockIdx.y * 128;
  const int bn   = blockIdx.x * 128;

  const unsigned short* ga[4];
  const unsigned short* gb[4];
  unsigned short* la[4];
  unsigned short* lbp[4];
#pragma unroll
  for (int i = 0; i < 4; ++i){
    int s0   = (wave * 4 + i) * 64;   // wave-uniform base slot
    int slot = s0 + lane;
    int row  = slot >> 3;
    int kb   = (slot & 7) ^ (row & 7);
    ga[i]  = A  + (size_t)(bm + row) * K + kb * 8;
    gb[i]  = Bt + (size_t)(bn + row) * K + kb * 8;
    la[i]  = lA + s0 * 8;
    lbp[i] = lB + s0 * 8;
  }

  int abase[4], bbase[4];
#pragma unroll
  for (int t = 0; t < 4; ++t){
    abase[t] = (wm * 64 + t * 16 + mm) * 8;
    bbase[t] = (wn * 64 + t * 16 + mm) * 8;
  }

  const f32x4 fzero = {0.f, 0.f, 0.f, 0.f};
  f32x4 acc[4][4];
#pragma unroll
  for (int i = 0; i < 4; ++i)
#pragma unroll
    for (int j = 0; j < 4; ++j) acc[i][j] = fzero;

  for (int k0 = 0; k0 < K; k0 += 64){
    __syncthreads();
#pragma unroll
    for (int i = 0; i < 4; ++i){
      gll16(ga[i] + k0, la[i]);
      gll16(gb[i] + k0, lbp[i]);
    }
    __syncthreads();
#pragma unroll
    for (int ks = 0; ks < 2; ++ks){
      const int co = (ks * 4 + qd) ^ m7;
      short8 af[4], bfv[4];
#pragma unroll
      for (int t = 0; t < 4; ++t) af[t]  = *(const short8*)(lA + (abase[t] + co) * 8);
#pragma unroll
      for (int t = 0; t < 4; ++t) bfv[t] = *(const short8*)(lB + (bbase[t] + co) * 8);
#pragma unroll
      for (int i = 0; i < 4; ++i)
#pragma unroll
        for (int j = 0; j < 4; ++j)
          acc[i][j] = __builtin_amdgcn_mfma_f32_16x16x32_bf16(af[i], bfv[j], acc[i][j], 0, 0, 0);
    }
  }

  if (MODE == 0 && bn >= 4096){
    // ---- V block: 128x128 tile transpose via LDS, coalesced Vt stores ----
    __syncthreads();   // all lA/lB fragment reads done before overwrite
    unsigned short* lT = lAB;   // [d=128][t-chunks 32][4] u16, chunk XOR swz
#pragma unroll
    for (int i = 0; i < 4; ++i){
#pragma unroll
      for (int j = 0; j < 4; ++j){
        const int d_l   = wn * 64 + j * 16 + mm;
        const int chunk = wm * 16 + i * 4 + qd;     // t_local>>2
        const int ch    = chunk ^ (d_l & 31);
        short4v pk;
#pragma unroll
        for (int r = 0; r < 4; ++r) pk[r] = (short)f2bf(acc[i][j][r]);
        *(short4v*)(lT + d_l * 128 + ch * 4) = pk;
      }
    }
    __syncthreads();
    const int hV = (bn >> 7) - 32;
    const int dd = tid >> 4;          // 0..15
    const int tg = tid & 15;          // 8-t group -> 16B store
#pragma unroll
    for (int p = 0; p < 8; ++p){
      const int d_l = p * 16 + dd;
      const int c0  = (tg * 2)     ^ (d_l & 31);
      const int c1  = (tg * 2 + 1) ^ (d_l & 31);
      short4v lo = *(const short4v*)(lT + d_l * 128 + c0 * 4);
      short4v hi = *(const short4v*)(lT + d_l * 128 + c1 * 4);
      short8 ov;
      ov[0] = lo[0]; ov[1] = lo[1]; ov[2] = lo[2]; ov[3] = lo[3];
      ov[4] = hi[0]; ov[5] = hi[1]; ov[6] = hi[2]; ov[7] = hi[3];
      *(short8*)(Vt + ((size_t)(hV * HD + d_l)) * T_SEQ + bm + tg * 8) = ov;
    }
    return;
  }

#pragma unroll
  for (int i = 0; i < 4; ++i){
#pragma unroll
    for (int j = 0; j < 4; ++j){
      const int col = bn + wn * 64 + j * 16 + mm;
#pragma unroll
      for (int r = 0; r < 4; ++r){
        const int row = bm + wm * 64 + i * 16 + qd * 4 + r;
        const float v = acc[i][j][r];
        if (MODE == 0){
          const int nn  = col & 2047;
          const int h   = nn >> 7;
          const int d   = nn & 127;
          const unsigned short bv = f2bf(v);
          if (col < 2048)      Qb[((size_t)h * T_SEQ + row) * HD + d] = bv;
          else                 Kb[((size_t)h * T_SEQ + row) * HD + d] = bv;
        } else {
          Cf[(size_t)row * NTOT + col] = v;
        }
      }
    }
  }
}

// ---------------- RoPE on Q and K (in place, bf16) ----------------
__global__ __launch_bounds__(256) void rope_k(unsigned short* __restrict__ Qb,
                                              unsigned short* __restrict__ Kb){
  const int j = threadIdx.x & 63;
  const int t = blockIdx.x * 4 + (threadIdx.x >> 6);
  const int h = blockIdx.y;
  const float fr = (float)t * __expf(-(float)j * (9.210340371976184f / 64.f));
  const float cs = cosf(fr), sn = sinf(fr);
  const size_t base = ((size_t)h * T_SEQ + t) * HD;
  {
    float x1 = bf2f(Qb[base + j]), x2 = bf2f(Qb[base + j + 64]);
    Qb[base + j]      = f2bf(x1 * cs - x2 * sn);
    Qb[base + j + 64] = f2bf(x2 * cs + x1 * sn);
  }
  {
    float x1 = bf2f(Kb[base + j]), x2 = bf2f(Kb[base + j + 64]);
    Kb[base + j]      = f2bf(x1 * cs - x2 * sn);
    Kb[base + j + 64] = f2bf(x2 * cs + x1 * sn);
  }
}

// ---------------- flash attention v11 (v10 + correct register budget) ----------------
// v10 post-mortem (R10): __launch_bounds__(256,4) capped VGPR at 64 vs ~150
// demand -> allocator spilled o/qf/St to scratch -> FETCH 26->587MB,
// WRITE 17->461MB (read~write = scratch signature), attn 443us. The swapped-
// QK^T + permuted-k structure itself PASSED correctness, and conflicts
// 9.7M -> 8.65M shows the lP path was ~1.1M of them. v11 = v10 with
// launch_bounds(256,3): VGPR cap ~170 fits the ~150-reg working set ->
// no spill, 3 blocks/CU (same as v8). Clean A/B of the lP-removal
// hypothesis vs v8's 132.4us.
//  - SWAPPED QK^T: St[nt][mt] = mfma(kf, qf); lane (qd,cc) holds P for
//    q-row cc at keys nt*16+qd*4+r = exactly its 8 PV A-slots.
//  - k-SLOT PERMUTATION (both sides): pf packs native 8 values (4 pk2, no
//    shuffles); vf read as two b64 halves carrying the same permuted keys.
//    MFMA contracts over slots -> permutation-invariant; ones-MFMA too.
//  - No lP: 16 stores + 2 b128 reads + RAW lgkm serialization removed/iter.
__global__ __launch_bounds__(256, 3) void attn_k(
    const unsigned short* __restrict__ Qb,   // [NH][T][HD]
    const unsigned short* __restrict__ Kb,   // [NH][T][HD]
    const unsigned short* __restrict__ Vt,   // [NH][HD][T]
    unsigned short* __restrict__ Yb)         // [T][HID]
{
  __shared__ __align__(16) unsigned char smem[35072];
  unsigned short* lK = (unsigned short*)smem;              // [64 keys][128 d] 16 KB
  unsigned short* lV = (unsigned short*)(smem + 16384);    // [128 d][64 keys] 16 KB
  float* lO = (float*)smem;                                // [128 d][68] epilogue overlay
  float* lL = (float*)(smem + 34816);                      // [64] (beyond lO)

  const int tid  = threadIdx.x;
  const int w    = tid >> 6;
  const int rg   = w >> 1;
  const int kg   = w & 1;
  const int lane = tid & 63;
  const int qd   = lane >> 4;
  const int cc   = lane & 15;
  const int cx   = cc & 7;
  const int r8   = lane >> 3, c7 = lane & 7;

  const int b  = blockIdx.x;            // 1024 blocks
  const int h  = b & 15;                // head; h&7 = b&7 -> XCD pinned
  const int tp = 63 - (b >> 4);         // big tiles dispatched first
  const int qrow0 = tp * 64 + rg * 32;
  const int iters = tp + 1;

  // staging source addressing (swizzle on fetch side; slot chunk c holds
  // global chunk c ^ (row&7))
  const int ce  = cc ^ qd;
  const int dlt = (ce & 4) ? -32 : 32;
  const unsigned short* gKbp = Kb + ((size_t)h * T_SEQ + w * 16 + qd) * HD + ce * 8;
  const int cV = c7 ^ r8;
  const unsigned short* gVbp = Vt + ((size_t)h * HD + w * 32 + r8) * T_SEQ + cV * 8;

  // vf half-chunk addressing (permuted-k layout): slot e<4 -> key qd*4+e,
  // slot e>=4 -> key 16+qd*4+(e&3), within kg's 32 keys.
  const int cgA = kg * 4 + (qd >> 1);       // global 8-key chunk of lower half
  const int vhalf = (qd & 1) * 4;           // 4-short offset within chunk

  const f32x4 fzero = {0.f, 0.f, 0.f, 0.f};
  // 50*tanh(s*SCALE/50)*log2(e) ~= s*(B0 + B1*s^2 + B2*s^4)
  const float B0 = 0.09016844006f;
  const float B1 = -4.6962728e-8f;
  const float B2 = 2.9351706e-14f;
  const float CLP = 72.134752f;        // 50 * log2(e)
  short8 onesv;
#pragma unroll
  for (int j = 0; j < 8; ++j) onesv[j] = (short)0x3F80;    // bf16 1.0

  // prologue: stage K(0), V(0)
  {
    unsigned short* dK = lK + w * 2048;
#pragma unroll
    for (int i = 0; i < 4; ++i)
      gll16(gKbp + (size_t)(i * 4) * HD + ((i & 1) ? dlt : 0), dK + i * 512);
    unsigned short* dV = lV + w * 2048;
#pragma unroll
    for (int i = 0; i < 4; ++i)
      gll16(gVbp + (size_t)i * 8 * T_SEQ, dV + i * 512);
  }

  // Q fragments: rows qrow0 + mt*16 + cc, d = ks*32 + qd*8 (B-operand now)
  short8 qf[2][4];
#pragma unroll
  for (int mt = 0; mt < 2; ++mt)
#pragma unroll
    for (int ks = 0; ks < 4; ++ks)
      qf[mt][ks] = *(const short8*)(Qb + ((size_t)h * T_SEQ + qrow0 + mt * 16 + cc) * HD + ks * 32 + qd * 8);

  f32x4 o[2][8];
  f32x4 acc_l[2];
#pragma unroll
  for (int mt = 0; mt < 2; ++mt){
#pragma unroll
    for (int dn = 0; dn < 8; ++dn) o[mt][dn] = fzero;
    acc_l[mt] = fzero;
  }

#pragma unroll 1
  for (int it = 0; it < iters; ++it){
    const int k0 = it * 64;
    VM_WAIT0;          // this wave's K(it)/V(it) landed
    barrier_fence();   // all waves' landed; tiles valid

    // St = (Q K^T)^T via swapped operands: St[nt][mt], lane holds
    // key = k0 + kg*32 + nt*16 + qd*4 + r, q-row = qrow0 + mt*16 + cc
    f32x4 St[2][2];
#pragma unroll
    for (int nt = 0; nt < 2; ++nt)
#pragma unroll
      for (int mt = 0; mt < 2; ++mt) St[nt][mt] = fzero;
    __builtin_amdgcn_s_setprio(1);
#pragma unroll
    for (int nt = 0; nt < 2; ++nt){
      short8 kf[4];
#pragma unroll
      for (int ks = 0; ks < 4; ++ks)
        kf[ks] = *(const short8*)(lK + ((kg * 32 + nt * 16 + cc) * 16 + ((ks * 4 + qd) ^ cx)) * 8);
#pragma unroll
      for (int mt = 0; mt < 2; ++mt)
#pragma unroll
        for (int ks = 0; ks < 4; ++ks)
          St[nt][mt] = __builtin_amdgcn_mfma_f32_16x16x32_bf16(kf[ks], qf[mt][ks], St[nt][mt], 0, 0, 0);
    }
    __builtin_amdgcn_s_setprio(0);

    // softcap + exp2 + causal mask (last iter), then in-register bf16 pack
    const bool domask = (it == iters - 1);
    short8 pf[2];
#pragma unroll
    for (int mt = 0; mt < 2; ++mt){
      float pv[2][4];
#pragma unroll
      for (int nt = 0; nt < 2; ++nt)
#pragma unroll
        for (int r = 0; r < 4; ++r){
          float s = St[nt][mt][r];
          float w2 = s * s;
          float t = fmaf(w2, B2, B1);
          t = fmaf(w2, t, B0);
          float a = s * t;
          a = __builtin_amdgcn_fmed3f(a, -CLP, CLP);
          float p = __builtin_amdgcn_exp2f(a);
          if (domask){
            int key = k0 + kg * 32 + nt * 16 + qd * 4 + r;
            int row = qrow0 + mt * 16 + cc;
            if (key > row) p = 0.f;
          }
          pv[nt][r] = p;
        }
      uint4v up;
      up[0] = pk2(pv[0][0], pv[0][1]);
      up[1] = pk2(pv[0][2], pv[0][3]);
      up[2] = pk2(pv[1][0], pv[1][1]);
      up[3] = pk2(pv[1][2], pv[1][3]);
      pf[mt] = __builtin_bit_cast(short8, up);
    }

    // O += P V (permuted-k vf: two b64 halves per dn) ; l += P . 1
    __builtin_amdgcn_s_setprio(1);
#pragma unroll
    for (int dn = 0; dn < 8; ++dn){
      const int drow = (dn * 16 + cc) * 8;
      short4v vlo = *(const short4v*)(lV + (drow + (cgA ^ cx)) * 8 + vhalf);
      short4v vhi = *(const short4v*)(lV + (drow + ((cgA + 2) ^ cx)) * 8 + vhalf);
      short8 vfv;
      vfv[0] = vlo[0]; vfv[1] = vlo[1]; vfv[2] = vlo[2]; vfv[3] = vlo[3];
      vfv[4] = vhi[0]; vfv[5] = vhi[1]; vfv[6] = vhi[2]; vfv[7] = vhi[3];
#pragma unroll
      for (int mt = 0; mt < 2; ++mt)
        o[mt][dn] = __builtin_amdgcn_mfma_f32_16x16x32_bf16(pf[mt], vfv, o[mt][dn], 0, 0, 0);
    }
#pragma unroll
    for (int mt = 0; mt < 2; ++mt)
      acc_l[mt] = __builtin_amdgcn_mfma_f32_16x16x32_bf16(pf[mt], onesv, acc_l[mt], 0, 0, 0);
    __builtin_amdgcn_s_setprio(0);

    // all lK/lV ds_reads retired, then barrier: next iter's global_load_lds
    // writes must not land before every wave's reads are done
    LGKM_WAIT0;
    barrier_fence();

    if (it + 1 < iters){
      const unsigned short* gK = gKbp + (size_t)(k0 + 64) * HD;
      unsigned short* dK = lK + w * 2048;
#pragma unroll
      for (int i = 0; i < 4; ++i)
        gll16(gK + (size_t)(i * 4) * HD + ((i & 1) ? dlt : 0), dK + i * 512);
      const unsigned short* gV = gVbp + (k0 + 64);
      unsigned short* dV = lV + w * 2048;
#pragma unroll
      for (int i = 0; i < 4; ++i)
        gll16(gV + (size_t)i * 8 * T_SEQ, dV + i * 512);
    }
  }

  // ---- epilogue: merge kg partials (additive), normalize, store ----
  // acc_l[mt][r] = row-sum for q-row mt*16+qd*4+r (same value in all cc)
  __syncthreads();   // all K/V traffic done before lO overlays the region
  if (kg == 1){
#pragma unroll
    for (int mt = 0; mt < 2; ++mt){
#pragma unroll
      for (int dn = 0; dn < 8; ++dn)
        *(f32x4*)&lO[(dn * 16 + cc) * 68 + rg * 32 + mt * 16 + qd * 4] = o[mt][dn];
      if (cc == 0){
#pragma unroll
        for (int r = 0; r < 4; ++r)
          lL[rg * 32 + mt * 16 + qd * 4 + r] = acc_l[mt][r];
      }
    }
  }
  __syncthreads();
  if (kg == 0){
#pragma unroll
    for (int mt = 0; mt < 2; ++mt){
      float inv[4];
#pragma unroll
      for (int r = 0; r < 4; ++r){
        float lt = acc_l[mt][r] + lL[rg * 32 + mt * 16 + qd * 4 + r];
        inv[r] = __builtin_amdgcn_rcpf(lt);
      }
#pragma unroll
      for (int dn = 0; dn < 8; ++dn){
        f32x4 oo = o[mt][dn] + *(const f32x4*)&lO[(dn * 16 + cc) * 68 + rg * 32 + mt * 16 + qd * 4];
#pragma unroll
        for (int r = 0; r < 4; ++r){
          int row = qrow0 + mt * 16 + qd * 4 + r;
          Yb[(size_t)row * HID + h * HD + dn * 16 + cc] = f2bf(oo[r] * inv[r]);
        }
      }
    }
  }
}

extern "C" void kernel_launch(void* const* d_in, const int* in_sizes, int n_in,
                              void* d_out, int out_size, void* d_ws, size_t ws_size,
                              hipStream_t stream) {
  const float* X  = (const float*)d_in[0];
  const float* Wq = (const float*)d_in[1];
  const float* Wk = (const float*)d_in[2];
  const float* Wv = (const float*)d_in[3];
  const float* Wo = (const float*)d_in[4];
  float* out = (float*)d_out;

  unsigned short* ws = (unsigned short*)d_ws;
  unsigned short* Xb = ws;                                   // [T][HID]        16 MiB
  unsigned short* Wt = ws + (size_t)8  * 1024 * 1024;        // [4*2048][2048]  32 MiB
  unsigned short* Qb = ws + (size_t)24 * 1024 * 1024;        // [NH][T][HD]     16 MiB
  unsigned short* Kb = ws + (size_t)32 * 1024 * 1024;        // [NH][T][HD]     16 MiB
  unsigned short* Vt = ws + (size_t)40 * 1024 * 1024;        // [NH][HD][T]     16 MiB
  unsigned short* Yb = Xb;                                   // reuse X region

  conv_x_k<<<8192, 256, 0, stream>>>(X, Xb);
  conv_wt_k<<<dim3(64, 64, 4), dim3(32, 8), 0, stream>>>(Wq, Wk, Wv, Wo, Wt);
  gemm_bt<0, 6144><<<dim3(48, 32), 256, 0, stream>>>(Xb, Wt, Qb, Kb, Vt, nullptr);
  rope_k<<<dim3(1024, NH), 256, 0, stream>>>(Qb, Kb);
  attn_k<<<dim3(1024), 256, 0, stream>>>(Qb, Kb, Vt, Yb);
  gemm_bt<1, 2048><<<dim3(16, 32), 256, 0, stream>>>(Yb, Wt + (size_t)6144 * 2048,
                                                     nullptr, nullptr, nullptr, out);
}